// Round 3
// baseline (582.690 us; speedup 1.0000x reference)
//
#include <hip/hip_runtime.h>
#include <stdint.h>

typedef short bf16x8 __attribute__((ext_vector_type(8)));
typedef float f32x4 __attribute__((ext_vector_type(4)));

// RNE float -> bf16 (raw bits in short)
__device__ __forceinline__ short f2bf(float f) {
  unsigned int u = __float_as_uint(f);
  u = (u + 0x7FFFu + ((u >> 16) & 1u)) >> 16;
  return (short)u;
}

// async global->LDS, 16B per lane. LDS dest = wave-uniform base + lane*16.
__device__ __forceinline__ void gload_lds16(const void* g, void* l) {
  __builtin_amdgcn_global_load_lds((const __attribute__((address_space(1))) void*)g,
                                   (__attribute__((address_space(3))) void*)l, 16, 0, 0);
}

// ---------------------------------------------------------------------------
// Prep kernels
// ---------------------------------------------------------------------------

__global__ void cvt_x_kernel(const float* __restrict__ in, short* __restrict__ out) {
  int i = blockIdx.x * 256 + threadIdx.x;
  float4 v = ((const float4*)in)[i];
  short4 o;
  o.x = f2bf(v.x); o.y = f2bf(v.y); o.z = f2bf(v.z); o.w = f2bf(v.w);
  ((short4*)out)[i] = o;
}

// out[c*ldout + r] = bf16(in[r][c]);  R,C multiples of 32
__global__ void transpose_f2b_kernel(const float* __restrict__ in, short* __restrict__ out,
                                     int R, int C, int ldout) {
  __shared__ float tile[32][33];
  int tx = threadIdx.x & 31, ty = threadIdx.x >> 5;
  int c0 = blockIdx.x * 32, r0 = blockIdx.y * 32;
#pragma unroll
  for (int j = 0; j < 4; j++)
    tile[ty + j * 8][tx] = in[(size_t)(r0 + ty + j * 8) * C + c0 + tx];
  __syncthreads();
#pragma unroll
  for (int j = 0; j < 4; j++)
    out[(size_t)(c0 + ty + j * 8) * ldout + r0 + tx] = f2bf(tile[tx][ty + j * 8]);
}

// vT[bh][d][l] = qkv[b*2048+l][2048 + h*64 + d]
__global__ void transpose_v_kernel(const short* __restrict__ qkv, short* __restrict__ vT) {
  __shared__ short tile[32][33];
  int tx = threadIdx.x & 31, ty = threadIdx.x >> 5;
  int l0 = blockIdx.x * 32, d0 = blockIdx.y * 32;
  int bh = blockIdx.z, b = bh >> 4, h = bh & 15;
#pragma unroll
  for (int j = 0; j < 4; j++)
    tile[ty + j * 8][tx] =
        qkv[(size_t)(b * 2048 + l0 + ty + j * 8) * 3072 + 2048 + h * 64 + d0 + tx];
  __syncthreads();
#pragma unroll
  for (int j = 0; j < 4; j++)
    vT[((size_t)bh * 64 + d0 + ty + j * 8) * 2048 + l0 + tx] = tile[tx][ty + j * 8];
}

// T5 relative-position bias table: btab[h][dist], dist = q - k in [0,2047]
__global__ void bias_kernel(const float* __restrict__ rel_emb, float* __restrict__ btab) {
  int i = blockIdx.x * 256 + threadIdx.x;  // 16*2048
  int h = i >> 11, n = i & 2047;
  int bucket;
  if (n < 16) {
    bucket = n;
  } else {
    float t = logf((float)n * 0.0625f) * (16.0f / 2.0794415416798357f);
    bucket = 16 + (int)t;
    if (bucket > 31) bucket = 31;
  }
  btab[i] = rel_emb[bucket * 16 + h];
}

// ---------------------------------------------------------------------------
// bf16 GEMM: C[M][N] = A[M][K] * Bt[N][K]^T.  128x128 tile, BK=64, 4 waves.
// global_load_lds(16B) staging, XOR-rotate chunk swizzle -> conflict-free.
// EPI: 0 = bf16 store, 1 = relu->bf16 store
// ---------------------------------------------------------------------------
template <int EPI>
__global__ __launch_bounds__(256, 3)
void gemm_bt_kernel(const short* __restrict__ A, const short* __restrict__ Bt,
                    int N, int K, short* __restrict__ Cb) {
  __shared__ short lA[128 * 64];
  __shared__ short lB[128 * 64];
  const int t = threadIdx.x;
  const int w = t >> 6, lane = t & 63;
  const int q4 = lane >> 4, l15 = lane & 15;
  const int mBase = blockIdx.y * 128, nBase = blockIdx.x * 128;
  const int wm = (w >> 1) * 64, wn = (w & 1) * 64;

  const f32x4 fzero = {0.f, 0.f, 0.f, 0.f};
  f32x4 acc[4][4];
#pragma unroll
  for (int i = 0; i < 4; i++)
#pragma unroll
    for (int j = 0; j < 4; j++) acc[i][j] = fzero;

  for (int k0 = 0; k0 < K; k0 += 64) {
    __syncthreads();
#pragma unroll
    for (int p = 0; p < 4; p++) {
      int c = p * 256 + t;
      int row = c >> 3;
      int kc = ((c & 7) - row) & 7;  // logical k-chunk stored at slot c&7
      gload_lds16(A + (size_t)(mBase + row) * K + k0 + kc * 8, lA + (size_t)(c - lane) * 8);
      gload_lds16(Bt + (size_t)(nBase + row) * K + k0 + kc * 8, lB + (size_t)(c - lane) * 8);
    }
    __syncthreads();
#pragma unroll
    for (int ks = 0; ks < 2; ks++) {
      bf16x8 af[4], bfr[4];
#pragma unroll
      for (int mi = 0; mi < 4; mi++) {
        int row = wm + mi * 16 + l15;
        af[mi] = *(const bf16x8*)&lA[row * 64 + ((ks * 4 + q4 + row) & 7) * 8];
      }
#pragma unroll
      for (int ni = 0; ni < 4; ni++) {
        int row = wn + ni * 16 + l15;
        bfr[ni] = *(const bf16x8*)&lB[row * 64 + ((ks * 4 + q4 + row) & 7) * 8];
      }
#pragma unroll
      for (int mi = 0; mi < 4; mi++)
#pragma unroll
        for (int ni = 0; ni < 4; ni++)
          acc[mi][ni] =
              __builtin_amdgcn_mfma_f32_16x16x32_bf16(af[mi], bfr[ni], acc[mi][ni], 0, 0, 0);
    }
  }

#pragma unroll
  for (int mi = 0; mi < 4; mi++)
#pragma unroll
    for (int ni = 0; ni < 4; ni++) {
#pragma unroll
      for (int r = 0; r < 4; r++) {
        size_t idx = (size_t)(mBase + wm + mi * 16 + q4 * 4 + r) * N +
                     (nBase + wn + ni * 16 + l15);
        float v = acc[mi][ni][r];
        if constexpr (EPI == 0) Cb[idx] = f2bf(v);
        else Cb[idx] = f2bf(v > 0.f ? v : 0.f);
      }
    }
}

// ---------------------------------------------------------------------------
// Fused final GEMM: out[M][1024] = [ctx | hidden] @ wcat^T + inputs
// A-K concatenated: k<1024 -> ctx[row][k] (ld 1024); else hidden[row][k-1024]
// (ld 4096). wcat: [1024 n][5120 k].  fp32 out.
// ---------------------------------------------------------------------------
__global__ __launch_bounds__(256, 3)
void gemm_cat_kernel(const short* __restrict__ ctx, const short* __restrict__ hidden,
                     const short* __restrict__ wcat, const float* __restrict__ resid,
                     float* __restrict__ out) {
  __shared__ short lA[128 * 64];
  __shared__ short lB[128 * 64];
  const int t = threadIdx.x;
  const int w = t >> 6, lane = t & 63;
  const int q4 = lane >> 4, l15 = lane & 15;
  const int mBase = blockIdx.y * 128, nBase = blockIdx.x * 128;
  const int wm = (w >> 1) * 64, wn = (w & 1) * 64;

  const f32x4 fzero = {0.f, 0.f, 0.f, 0.f};
  f32x4 acc[4][4];
#pragma unroll
  for (int i = 0; i < 4; i++)
#pragma unroll
    for (int j = 0; j < 4; j++) acc[i][j] = fzero;

  for (int k0 = 0; k0 < 5120; k0 += 64) {
    const short* Abase = (k0 < 1024) ? (ctx + k0) : (hidden + (k0 - 1024));
    const size_t lda = (k0 < 1024) ? 1024 : 4096;
    __syncthreads();
#pragma unroll
    for (int p = 0; p < 4; p++) {
      int c = p * 256 + t;
      int row = c >> 3;
      int kc = ((c & 7) - row) & 7;
      gload_lds16(Abase + (size_t)(mBase + row) * lda + kc * 8, lA + (size_t)(c - lane) * 8);
      gload_lds16(wcat + (size_t)(nBase + row) * 5120 + k0 + kc * 8,
                  lB + (size_t)(c - lane) * 8);
    }
    __syncthreads();
#pragma unroll
    for (int ks = 0; ks < 2; ks++) {
      bf16x8 af[4], bfr[4];
#pragma unroll
      for (int mi = 0; mi < 4; mi++) {
        int row = wm + mi * 16 + l15;
        af[mi] = *(const bf16x8*)&lA[row * 64 + ((ks * 4 + q4 + row) & 7) * 8];
      }
#pragma unroll
      for (int ni = 0; ni < 4; ni++) {
        int row = wn + ni * 16 + l15;
        bfr[ni] = *(const bf16x8*)&lB[row * 64 + ((ks * 4 + q4 + row) & 7) * 8];
      }
#pragma unroll
      for (int mi = 0; mi < 4; mi++)
#pragma unroll
        for (int ni = 0; ni < 4; ni++)
          acc[mi][ni] =
              __builtin_amdgcn_mfma_f32_16x16x32_bf16(af[mi], bfr[ni], acc[mi][ni], 0, 0, 0);
    }
  }

#pragma unroll
  for (int mi = 0; mi < 4; mi++)
#pragma unroll
    for (int ni = 0; ni < 4; ni++) {
#pragma unroll
      for (int r = 0; r < 4; r++) {
        size_t idx = (size_t)(mBase + wm + mi * 16 + q4 * 4 + r) * 1024 +
                     (nBase + wn + ni * 16 + l15);
        out[idx] = acc[mi][ni][r] + resid[idx];
      }
    }
}

// ---------------------------------------------------------------------------
// Flash attention, causal + T5 relpos bias.  K-tile 128, Q-tile 64, 4 waves.
// XOR-rotate swizzled LDS (conflict-free), 49.9 KB -> 3 blocks/CU.
// ---------------------------------------------------------------------------
__global__ __launch_bounds__(256, 3)
void attn_kernel(const short* __restrict__ qkv, const short* __restrict__ vT,
                 const float* __restrict__ bias_tab, short* __restrict__ ctx) {
  __shared__ short lK[128 * 64];     // [kpos][d], swizzle-8
  __shared__ short lV[64 * 128];     // [d][kpos], swizzle-16
  __shared__ short lP[4][16 * 128];  // per-wave P round-trip, swizzle-16
  __shared__ float lBias[192];

  const int t = threadIdx.x, w = t >> 6, lane = t & 63;
  const int q4 = lane >> 4, l15 = lane & 15;
  const int bh = blockIdx.x;            // 0..63
  const int qt = 31 - blockIdx.y;       // heavy blocks first
  const int b = bh >> 4, h = bh & 15;
  const int q0 = qt * 64;
  const int ntiles = (qt + 2) >> 1;     // 128-wide K tiles covering [0, q0+64)
  const f32x4 fzero = {0.f, 0.f, 0.f, 0.f};

  // Q A-fragments, rows q0 + w*16 + l15
  const size_t qrow = (size_t)(b * 2048 + q0 + w * 16 + l15) * 3072 + h * 64;
  bf16x8 aq0 = *(const bf16x8*)(qkv + qrow + q4 * 8);
  bf16x8 aq1 = *(const bf16x8*)(qkv + qrow + 32 + q4 * 8);

  f32x4 vacc[4];
#pragma unroll
  for (int db = 0; db < 4; db++) vacc[db] = fzero;
  float m_old[4], l_sum[4];
#pragma unroll
  for (int r = 0; r < 4; r++) { m_old[r] = -3.0e38f; l_sum[r] = 0.f; }

  const float* btab = bias_tab + h * 2048;
  const int ksr = t >> 1;               // K staging row 0..127
  const int klc = (t & 1) * 4;          // K logical chunk base (of 8)
  const int vsr = t >> 2;               // V staging row 0..63
  const int vlc = (t & 3) * 4;          // V logical chunk base (of 16)
  const int qrow0 = q0 + w * 16 + q4 * 4;
  const int bofs = w * 16 + q4 * 4 + 127 - l15;
  const float L2E = 1.44269504088896f;

  int4 rk0, rk1, rk2, rk3, rv0, rv1, rv2, rv3;
  float biasreg;
  {
    const short* kp = qkv + (size_t)(b * 2048 + ksr) * 3072 + 1024 + h * 64 + klc * 8;
    rk0 = *(const int4*)kp; rk1 = *(const int4*)(kp + 8);
    rk2 = *(const int4*)(kp + 16); rk3 = *(const int4*)(kp + 24);
    const short* vp = vT + ((size_t)bh * 64 + vsr) * 2048 + vlc * 8;
    rv0 = *(const int4*)vp; rv1 = *(const int4*)(vp + 8);
    rv2 = *(const int4*)(vp + 16); rv3 = *(const int4*)(vp + 24);
    int d = q0 - 127 + t;
    d = d < 0 ? 0 : (d > 2047 ? 2047 : d);
    biasreg = btab[d];
  }

  for (int kt = 0; kt < ntiles; kt++) {
    __syncthreads();  // prior tile's LDS reads done
    *(int4*)&lK[ksr * 64 + (((klc + 0) + ksr) & 7) * 8] = rk0;
    *(int4*)&lK[ksr * 64 + (((klc + 1) + ksr) & 7) * 8] = rk1;
    *(int4*)&lK[ksr * 64 + (((klc + 2) + ksr) & 7) * 8] = rk2;
    *(int4*)&lK[ksr * 64 + (((klc + 3) + ksr) & 7) * 8] = rk3;
    *(int4*)&lV[vsr * 128 + (((vlc + 0) + vsr) & 15) * 8] = rv0;
    *(int4*)&lV[vsr * 128 + (((vlc + 1) + vsr) & 15) * 8] = rv1;
    *(int4*)&lV[vsr * 128 + (((vlc + 2) + vsr) & 15) * 8] = rv2;
    *(int4*)&lV[vsr * 128 + (((vlc + 3) + vsr) & 15) * 8] = rv3;
    if (t < 192) lBias[t] = biasreg;
    __syncthreads();  // staging visible

    if (kt + 1 < ntiles) {  // prefetch next tile — hides behind compute
      const short* kp =
          qkv + (size_t)(b * 2048 + (kt + 1) * 128 + ksr) * 3072 + 1024 + h * 64 + klc * 8;
      rk0 = *(const int4*)kp; rk1 = *(const int4*)(kp + 8);
      rk2 = *(const int4*)(kp + 16); rk3 = *(const int4*)(kp + 24);
      const short* vp = vT + ((size_t)bh * 64 + vsr) * 2048 + (kt + 1) * 128 + vlc * 8;
      rv0 = *(const int4*)vp; rv1 = *(const int4*)(vp + 8);
      rv2 = *(const int4*)(vp + 16); rv3 = *(const int4*)(vp + 24);
      int d = q0 - (kt + 1) * 128 - 127 + t;
      d = d < 0 ? 0 : (d > 2047 ? 2047 : d);
      biasreg = btab[d];
    }

    // S = Q K^T  (8 col-blocks of 16)
    float s[8][4];
#pragma unroll
    for (int nb = 0; nb < 8; nb++) {
      int row = nb * 16 + l15;
      bf16x8 bk0 = *(const bf16x8*)&lK[row * 64 + ((q4 + row) & 7) * 8];
      bf16x8 bk1 = *(const bf16x8*)&lK[row * 64 + ((q4 + 4 + row) & 7) * 8];
      f32x4 f = fzero;
      f = __builtin_amdgcn_mfma_f32_16x16x32_bf16(aq0, bk0, f, 0, 0, 0);
      f = __builtin_amdgcn_mfma_f32_16x16x32_bf16(aq1, bk1, f, 0, 0, 0);
#pragma unroll
      for (int r = 0; r < 4; r++) s[nb][r] = f[r];
    }

    // scale + bias (LDS) + causal mask
#pragma unroll
    for (int nb = 0; nb < 8; nb++) {
      const int kcol = kt * 128 + nb * 16 + l15;
#pragma unroll
      for (int r = 0; r < 4; r++) {
        int dist = (qrow0 + r) - kcol;
        float bv = lBias[bofs + r - nb * 16];
        float sv = s[nb][r] * 0.125f + bv;
        s[nb][r] = (dist < 0) ? -3.0e38f : sv;
      }
    }

    // online softmax
    float mnew[4], alpha[4];
#pragma unroll
    for (int r = 0; r < 4; r++) {
      float mx = s[0][r];
#pragma unroll
      for (int nb = 1; nb < 8; nb++) mx = fmaxf(mx, s[nb][r]);
      mx = fmaxf(mx, __shfl_xor(mx, 1));
      mx = fmaxf(mx, __shfl_xor(mx, 2));
      mx = fmaxf(mx, __shfl_xor(mx, 4));
      mx = fmaxf(mx, __shfl_xor(mx, 8));
      mnew[r] = fmaxf(m_old[r], mx);
      alpha[r] = __builtin_amdgcn_exp2f((m_old[r] - mnew[r]) * L2E);
      m_old[r] = mnew[r];
    }
#pragma unroll
    for (int nb = 0; nb < 8; nb++)
#pragma unroll
      for (int r = 0; r < 4; r++)
        s[nb][r] = __builtin_amdgcn_exp2f((s[nb][r] - mnew[r]) * L2E);
#pragma unroll
    for (int r = 0; r < 4; r++) {
      float ps = s[0][r];
#pragma unroll
      for (int nb = 1; nb < 8; nb++) ps += s[nb][r];
      ps += __shfl_xor(ps, 1);
      ps += __shfl_xor(ps, 2);
      ps += __shfl_xor(ps, 4);
      ps += __shfl_xor(ps, 8);
      l_sum[r] = l_sum[r] * alpha[r] + ps;
    }
#pragma unroll
    for (int db = 0; db < 4; db++)
#pragma unroll
      for (int r = 0; r < 4; r++) vacc[db][r] *= alpha[r];

    // P: C-layout -> LDS -> A-layout (per-wave, swizzle-16)
    short* lPw = lP[w];
#pragma unroll
    for (int nb = 0; nb < 8; nb++) {
      int c = nb * 2 + (l15 >> 3);
#pragma unroll
      for (int r = 0; r < 4; r++) {
        int row = q4 * 4 + r;
        lPw[row * 128 + ((c + row) & 15) * 8 + (l15 & 7)] = f2bf(s[nb][r]);
      }
    }

    bf16x8 ap[4];
#pragma unroll
    for (int ks2 = 0; ks2 < 4; ks2++)
      ap[ks2] = *(const bf16x8*)&lPw[l15 * 128 + ((ks2 * 4 + q4 + l15) & 15) * 8];
#pragma unroll
    for (int db = 0; db < 4; db++) {
      int row = db * 16 + l15;
#pragma unroll
      for (int ks2 = 0; ks2 < 4; ks2++) {
        bf16x8 bv = *(const bf16x8*)&lV[row * 128 + ((ks2 * 4 + q4 + row) & 15) * 8];
        vacc[db] = __builtin_amdgcn_mfma_f32_16x16x32_bf16(ap[ks2], bv, vacc[db], 0, 0, 0);
      }
    }
  }

  float inv[4];
#pragma unroll
  for (int r = 0; r < 4; r++) inv[r] = 1.0f / l_sum[r];
#pragma unroll
  for (int db = 0; db < 4; db++)
#pragma unroll
    for (int r = 0; r < 4; r++) {
      size_t idx = (size_t)(b * 2048 + q0 + w * 16 + q4 * 4 + r) * 1024 +
                   h * 64 + db * 16 + l15;
      ctx[idx] = f2bf(vacc[db][r] * inv[r]);
    }
}

// ---------------------------------------------------------------------------
// Launch
// ---------------------------------------------------------------------------
extern "C" void kernel_launch(void* const* d_in, const int* in_sizes, int n_in,
                              void* d_out, int out_size, void* d_ws, size_t ws_size,
                              hipStream_t stream) {
  (void)in_sizes; (void)n_in; (void)out_size; (void)ws_size;
  const float* inputs  = (const float*)d_in[0];
  const float* wq      = (const float*)d_in[1];
  const float* wk      = (const float*)d_in[2];
  const float* wv      = (const float*)d_in[3];
  const float* wo      = (const float*)d_in[4];
  const float* wi      = (const float*)d_in[5];
  const float* wmo     = (const float*)d_in[6];
  const float* rel_emb = (const float*)d_in[7];
  float* out = (float*)d_out;
  char* ws = (char*)d_ws;

  const size_t MB = 1ull << 20;
  short* x16    = (short*)(ws + 0);         // 16 MB  [8192][1024]
  short* qkv    = (short*)(ws + 16 * MB);   // 48 MB  [8192][3072]
  short* hidden = (short*)(ws + 16 * MB);   // 64 MB  [8192][4096] overlay (qkv+vT dead)
  short* vT     = (short*)(ws + 64 * MB);   // 16 MB  [64][64][2048]
  short* wqkvt  = (short*)(ws + 80 * MB);   // 6 MB   [3072][1024]
  short* wit    = (short*)(ws + 86 * MB);   // 8 MB   [4096][1024]
  short* wcat   = (short*)(ws + 94 * MB);   // 10.5MB [1024][5120] = [wo^T | wmo^T]
  float* btab   = (float*)(ws + 105 * MB);  // 128 KB [16][2048]
  short* ctx    = (short*)(ws + 106 * MB);  // 16 MB  [8192][1024]

  cvt_x_kernel<<<8192, 256, 0, stream>>>(inputs, x16);
  transpose_f2b_kernel<<<dim3(32, 32), 256, 0, stream>>>(wq, wqkvt, 1024, 1024, 1024);
  transpose_f2b_kernel<<<dim3(32, 32), 256, 0, stream>>>(wk, wqkvt + 1024 * 1024, 1024, 1024, 1024);
  transpose_f2b_kernel<<<dim3(32, 32), 256, 0, stream>>>(wv, wqkvt + 2 * 1024 * 1024, 1024, 1024, 1024);
  transpose_f2b_kernel<<<dim3(128, 32), 256, 0, stream>>>(wi, wit, 1024, 4096, 1024);
  transpose_f2b_kernel<<<dim3(32, 32), 256, 0, stream>>>(wo, wcat, 1024, 1024, 5120);
  transpose_f2b_kernel<<<dim3(32, 128), 256, 0, stream>>>(wmo, wcat + 1024, 4096, 1024, 5120);
  bias_kernel<<<128, 256, 0, stream>>>(rel_emb, btab);

  // qkv = x @ [wq|wk|wv]
  gemm_bt_kernel<0><<<dim3(24, 64), 256, 0, stream>>>(x16, wqkvt, 3072, 1024, qkv);
  transpose_v_kernel<<<dim3(64, 2, 64), 256, 0, stream>>>(qkv, vT);
  attn_kernel<<<dim3(64, 32), 256, 0, stream>>>(qkv, vT, btab, ctx);
  // hidden = relu(x @ wi)
  gemm_bt_kernel<1><<<dim3(32, 64), 256, 0, stream>>>(x16, wit, 4096, 1024, hidden);
  // out = [ctx|hidden] @ wcat^T + inputs
  gemm_cat_kernel<<<dim3(8, 64), 256, 0, stream>>>(ctx, hidden, wcat, inputs, out);
}

// Round 4
// 489.822 us; speedup vs baseline: 1.1896x; 1.1896x over previous
//
#include <hip/hip_runtime.h>
#include <stdint.h>

typedef short bf16x8 __attribute__((ext_vector_type(8)));
typedef float f32x4 __attribute__((ext_vector_type(4)));

// RNE float -> bf16 (raw bits in short)
__device__ __forceinline__ short f2bf(float f) {
  unsigned int u = __float_as_uint(f);
  u = (u + 0x7FFFu + ((u >> 16) & 1u)) >> 16;
  return (short)u;
}

// async global->LDS, 16B per lane. LDS dest = wave-uniform base + lane*16.
__device__ __forceinline__ void gload_lds16(const void* g, void* l) {
  __builtin_amdgcn_global_load_lds((const __attribute__((address_space(1))) void*)g,
                                   (__attribute__((address_space(3))) void*)l, 16, 0, 0);
}
// async global->LDS, 4B per lane. LDS dest = wave-uniform base + lane*4.
__device__ __forceinline__ void gload_lds4(const void* g, void* l) {
  __builtin_amdgcn_global_load_lds((const __attribute__((address_space(1))) void*)g,
                                   (__attribute__((address_space(3))) void*)l, 4, 0, 0);
}

// ---------------------------------------------------------------------------
// Prep kernels
// ---------------------------------------------------------------------------

__global__ void cvt_x_kernel(const float* __restrict__ in, short* __restrict__ out) {
  int i = blockIdx.x * 256 + threadIdx.x;
  float4 v = ((const float4*)in)[i];
  short4 o;
  o.x = f2bf(v.x); o.y = f2bf(v.y); o.z = f2bf(v.z); o.w = f2bf(v.w);
  ((short4*)out)[i] = o;
}

// out[c*ldout + r] = bf16(in[r][c]);  R,C multiples of 32
__global__ void transpose_f2b_kernel(const float* __restrict__ in, short* __restrict__ out,
                                     int R, int C, int ldout) {
  __shared__ float tile[32][33];
  int tx = threadIdx.x & 31, ty = threadIdx.x >> 5;
  int c0 = blockIdx.x * 32, r0 = blockIdx.y * 32;
#pragma unroll
  for (int j = 0; j < 4; j++)
    tile[ty + j * 8][tx] = in[(size_t)(r0 + ty + j * 8) * C + c0 + tx];
  __syncthreads();
#pragma unroll
  for (int j = 0; j < 4; j++)
    out[(size_t)(c0 + ty + j * 8) * ldout + r0 + tx] = f2bf(tile[tx][ty + j * 8]);
}

// vT[bh][d][l] = qkv[b*2048+l][2048 + h*64 + d]
__global__ void transpose_v_kernel(const short* __restrict__ qkv, short* __restrict__ vT) {
  __shared__ short tile[32][33];
  int tx = threadIdx.x & 31, ty = threadIdx.x >> 5;
  int l0 = blockIdx.x * 32, d0 = blockIdx.y * 32;
  int bh = blockIdx.z, b = bh >> 4, h = bh & 15;
#pragma unroll
  for (int j = 0; j < 4; j++)
    tile[ty + j * 8][tx] =
        qkv[(size_t)(b * 2048 + l0 + ty + j * 8) * 3072 + 2048 + h * 64 + d0 + tx];
  __syncthreads();
#pragma unroll
  for (int j = 0; j < 4; j++)
    vT[((size_t)bh * 64 + d0 + ty + j * 8) * 2048 + l0 + tx] = tile[tx][ty + j * 8];
}

// T5 relative-position bias table, PRE-SCALED for exp2 fixed-shift softmax:
// btab[h][dist] = bias * log2(e) - 20*log2(e)
__global__ void bias_kernel(const float* __restrict__ rel_emb, float* __restrict__ btab) {
  int i = blockIdx.x * 256 + threadIdx.x;  // 16*2048
  int h = i >> 11, n = i & 2047;
  int bucket;
  if (n < 16) {
    bucket = n;
  } else {
    float t = logf((float)n * 0.0625f) * (16.0f / 2.0794415416798357f);
    bucket = 16 + (int)t;
    if (bucket > 31) bucket = 31;
  }
  btab[i] = rel_emb[bucket * 16 + h] * 1.4426950408889634f - 28.853900817779268f;
}

// ---------------------------------------------------------------------------
// bf16 GEMM: C[M][N] = A[M][K] * Bt[N][K]^T.  128x128 tile, BK=64, 4 waves.
// global_load_lds(16B) staging, XOR-rotate chunk swizzle -> conflict-free.
// EPI: 0 = bf16 store, 1 = relu->bf16 store
// ---------------------------------------------------------------------------
template <int EPI>
__global__ __launch_bounds__(256, 3)
void gemm_bt_kernel(const short* __restrict__ A, const short* __restrict__ Bt,
                    int N, int K, short* __restrict__ Cb) {
  __shared__ short lA[128 * 64];
  __shared__ short lB[128 * 64];
  const int t = threadIdx.x;
  const int w = t >> 6, lane = t & 63;
  const int q4 = lane >> 4, l15 = lane & 15;
  const int mBase = blockIdx.y * 128, nBase = blockIdx.x * 128;
  const int wm = (w >> 1) * 64, wn = (w & 1) * 64;

  const f32x4 fzero = {0.f, 0.f, 0.f, 0.f};
  f32x4 acc[4][4];
#pragma unroll
  for (int i = 0; i < 4; i++)
#pragma unroll
    for (int j = 0; j < 4; j++) acc[i][j] = fzero;

  for (int k0 = 0; k0 < K; k0 += 64) {
    __syncthreads();
#pragma unroll
    for (int p = 0; p < 4; p++) {
      int c = p * 256 + t;
      int row = c >> 3;
      int kc = ((c & 7) - row) & 7;  // logical k-chunk stored at slot c&7
      gload_lds16(A + (size_t)(mBase + row) * K + k0 + kc * 8, lA + (size_t)(c - lane) * 8);
      gload_lds16(Bt + (size_t)(nBase + row) * K + k0 + kc * 8, lB + (size_t)(c - lane) * 8);
    }
    __syncthreads();
#pragma unroll
    for (int ks = 0; ks < 2; ks++) {
      bf16x8 af[4], bfr[4];
#pragma unroll
      for (int mi = 0; mi < 4; mi++) {
        int row = wm + mi * 16 + l15;
        af[mi] = *(const bf16x8*)&lA[row * 64 + ((ks * 4 + q4 + row) & 7) * 8];
      }
#pragma unroll
      for (int ni = 0; ni < 4; ni++) {
        int row = wn + ni * 16 + l15;
        bfr[ni] = *(const bf16x8*)&lB[row * 64 + ((ks * 4 + q4 + row) & 7) * 8];
      }
#pragma unroll
      for (int mi = 0; mi < 4; mi++)
#pragma unroll
        for (int ni = 0; ni < 4; ni++)
          acc[mi][ni] =
              __builtin_amdgcn_mfma_f32_16x16x32_bf16(af[mi], bfr[ni], acc[mi][ni], 0, 0, 0);
    }
  }

#pragma unroll
  for (int mi = 0; mi < 4; mi++)
#pragma unroll
    for (int ni = 0; ni < 4; ni++) {
#pragma unroll
      for (int r = 0; r < 4; r++) {
        size_t idx = (size_t)(mBase + wm + mi * 16 + q4 * 4 + r) * N +
                     (nBase + wn + ni * 16 + l15);
        float v = acc[mi][ni][r];
        if constexpr (EPI == 0) Cb[idx] = f2bf(v);
        else Cb[idx] = f2bf(v > 0.f ? v : 0.f);
      }
    }
}

// ---------------------------------------------------------------------------
// Fused final GEMM: out[M][1024] = [ctx | hidden] @ wcat^T + inputs
// ---------------------------------------------------------------------------
__global__ __launch_bounds__(256, 3)
void gemm_cat_kernel(const short* __restrict__ ctx, const short* __restrict__ hidden,
                     const short* __restrict__ wcat, const float* __restrict__ resid,
                     float* __restrict__ out) {
  __shared__ short lA[128 * 64];
  __shared__ short lB[128 * 64];
  const int t = threadIdx.x;
  const int w = t >> 6, lane = t & 63;
  const int q4 = lane >> 4, l15 = lane & 15;
  const int mBase = blockIdx.y * 128, nBase = blockIdx.x * 128;
  const int wm = (w >> 1) * 64, wn = (w & 1) * 64;

  const f32x4 fzero = {0.f, 0.f, 0.f, 0.f};
  f32x4 acc[4][4];
#pragma unroll
  for (int i = 0; i < 4; i++)
#pragma unroll
    for (int j = 0; j < 4; j++) acc[i][j] = fzero;

  for (int k0 = 0; k0 < 5120; k0 += 64) {
    const short* Abase = (k0 < 1024) ? (ctx + k0) : (hidden + (k0 - 1024));
    const size_t lda = (k0 < 1024) ? 1024 : 4096;
    __syncthreads();
#pragma unroll
    for (int p = 0; p < 4; p++) {
      int c = p * 256 + t;
      int row = c >> 3;
      int kc = ((c & 7) - row) & 7;
      gload_lds16(Abase + (size_t)(mBase + row) * lda + kc * 8, lA + (size_t)(c - lane) * 8);
      gload_lds16(wcat + (size_t)(nBase + row) * 5120 + k0 + kc * 8,
                  lB + (size_t)(c - lane) * 8);
    }
    __syncthreads();
#pragma unroll
    for (int ks = 0; ks < 2; ks++) {
      bf16x8 af[4], bfr[4];
#pragma unroll
      for (int mi = 0; mi < 4; mi++) {
        int row = wm + mi * 16 + l15;
        af[mi] = *(const bf16x8*)&lA[row * 64 + ((ks * 4 + q4 + row) & 7) * 8];
      }
#pragma unroll
      for (int ni = 0; ni < 4; ni++) {
        int row = wn + ni * 16 + l15;
        bfr[ni] = *(const bf16x8*)&lB[row * 64 + ((ks * 4 + q4 + row) & 7) * 8];
      }
#pragma unroll
      for (int mi = 0; mi < 4; mi++)
#pragma unroll
        for (int ni = 0; ni < 4; ni++)
          acc[mi][ni] =
              __builtin_amdgcn_mfma_f32_16x16x32_bf16(af[mi], bfr[ni], acc[mi][ni], 0, 0, 0);
    }
  }

#pragma unroll
  for (int mi = 0; mi < 4; mi++)
#pragma unroll
    for (int ni = 0; ni < 4; ni++) {
#pragma unroll
      for (int r = 0; r < 4; r++) {
        size_t idx = (size_t)(mBase + wm + mi * 16 + q4 * 4 + r) * 1024 +
                     (nBase + wn + ni * 16 + l15);
        out[idx] = acc[mi][ni][r] + resid[idx];
      }
    }
}

// ---------------------------------------------------------------------------
// Flash attention, causal + T5 relpos bias.  K-tile 128, Q-tile 64, 4 waves.
// global_load_lds staging (no prefetch VGPRs -> no spill at 3 blocks/CU),
// XOR-rotate swizzled LDS (conflict-free), fixed-shift softmax:
//   p = exp2(s*0.125*log2e + biaspre)  with biaspre = bias*log2e - 20*log2e.
// Mathematically identical to max-subtracted softmax (relative fp precision
// is scale-invariant; s bounded well inside exp2's range). No in-loop
// reductions: l_sum lane-reduced once in the epilogue.
// ---------------------------------------------------------------------------
__global__ __launch_bounds__(256, 3)
void attn_kernel(const short* __restrict__ qkv, const short* __restrict__ vT,
                 const float* __restrict__ bias_tab, short* __restrict__ ctx) {
  __shared__ short lK[128 * 64];     // [kpos][d], swizzle-8
  __shared__ short lV[64 * 128];     // [d][kpos], swizzle-16
  __shared__ short lP[4][16 * 128];  // per-wave P round-trip, swizzle-16
  __shared__ float lBias[192];

  const int t = threadIdx.x, w = t >> 6, lane = t & 63;
  const int q4 = lane >> 4, l15 = lane & 15;
  const int bh = blockIdx.x;            // 0..63
  const int qt = 31 - blockIdx.y;       // heavy blocks first
  const int b = bh >> 4, h = bh & 15;
  const int q0 = qt * 64;
  const int ntiles = (qt + 2) >> 1;     // 128-wide K tiles covering [0, q0+64)
  const f32x4 fzero = {0.f, 0.f, 0.f, 0.f};
  const float C1 = 0.125f * 1.4426950408889634f;  // score scale * log2(e)

  // Q A-fragments, rows q0 + w*16 + l15
  const size_t qrow = (size_t)(b * 2048 + q0 + w * 16 + l15) * 3072 + h * 64;
  bf16x8 aq0 = *(const bf16x8*)(qkv + qrow + q4 * 8);
  bf16x8 aq1 = *(const bf16x8*)(qkv + qrow + 32 + q4 * 8);

  f32x4 vacc[4];
#pragma unroll
  for (int db = 0; db < 4; db++) vacc[db] = fzero;
  float l_part[4] = {0.f, 0.f, 0.f, 0.f};

  const float* btab = bias_tab + h * 2048;
  const int qrow0 = q0 + w * 16 + q4 * 4;
  const int bofs = w * 16 + q4 * 4 + 127 - l15;

  for (int kt = 0; kt < ntiles; kt++) {
    __syncthreads();  // prior tile's LDS reads done
    // K tile: 128 rows x 64 d, swizzle-8 (adjust GLOBAL chunk per lane)
#pragma unroll
    for (int p = 0; p < 4; p++) {
      int c = p * 256 + t;
      int row = c >> 3;
      int kc = ((c & 7) - row) & 7;
      gload_lds16(qkv + (size_t)(b * 2048 + kt * 128 + row) * 3072 + 1024 + h * 64 + kc * 8,
                  lK + (size_t)(c - lane) * 8);
    }
    // V^T tile: 64 d x 128 kpos, swizzle-16
#pragma unroll
    for (int p = 0; p < 4; p++) {
      int c = p * 256 + t;
      int d = c >> 4;
      int vc = ((c & 15) - d) & 15;
      gload_lds16(vT + ((size_t)bh * 64 + d) * 2048 + kt * 128 + vc * 8,
                  lV + (size_t)(c - lane) * 8);
    }
    // bias row (192 floats), waves 0..2
    if (w < 3) {
      int d = q0 - kt * 128 - 127 + t;
      d = d < 0 ? 0 : (d > 2047 ? 2047 : d);
      gload_lds4(btab + d, lBias + (t - lane));
    }
    __syncthreads();  // staging visible (barrier drains vmcnt)

    // S = Q K^T ; p = exp2(S*C1 + biaspre) ; causal mask -> 0
    float pr[8][4];
#pragma unroll
    for (int nb = 0; nb < 8; nb++) {
      int row = nb * 16 + l15;
      bf16x8 bk0 = *(const bf16x8*)&lK[row * 64 + ((q4 + row) & 7) * 8];
      bf16x8 bk1 = *(const bf16x8*)&lK[row * 64 + ((q4 + 4 + row) & 7) * 8];
      f32x4 f = fzero;
      f = __builtin_amdgcn_mfma_f32_16x16x32_bf16(aq0, bk0, f, 0, 0, 0);
      f = __builtin_amdgcn_mfma_f32_16x16x32_bf16(aq1, bk1, f, 0, 0, 0);
      const int kcol = kt * 128 + row;
#pragma unroll
      for (int r = 0; r < 4; r++) {
        int dist = (qrow0 + r) - kcol;
        float tv = f[r] * C1 + lBias[bofs + r - nb * 16];
        float pv = __builtin_amdgcn_exp2f(tv);
        pv = (dist < 0) ? 0.f : pv;
        pr[nb][r] = pv;
        l_part[r] += pv;
      }
    }

    // P: C-layout -> LDS -> A-layout (per-wave, swizzle-16)
    short* lPw = lP[w];
#pragma unroll
    for (int nb = 0; nb < 8; nb++) {
      int c = nb * 2 + (l15 >> 3);
#pragma unroll
      for (int r = 0; r < 4; r++) {
        int row = q4 * 4 + r;
        lPw[row * 128 + ((c + row) & 15) * 8 + (l15 & 7)] = f2bf(pr[nb][r]);
      }
    }

    bf16x8 ap[4];
#pragma unroll
    for (int ks2 = 0; ks2 < 4; ks2++)
      ap[ks2] = *(const bf16x8*)&lPw[l15 * 128 + ((ks2 * 4 + q4 + l15) & 15) * 8];
#pragma unroll
    for (int db = 0; db < 4; db++) {
      int row = db * 16 + l15;
#pragma unroll
      for (int ks2 = 0; ks2 < 4; ks2++) {
        bf16x8 bv = *(const bf16x8*)&lV[row * 128 + ((ks2 * 4 + q4 + row) & 15) * 8];
        vacc[db] = __builtin_amdgcn_mfma_f32_16x16x32_bf16(ap[ks2], bv, vacc[db], 0, 0, 0);
      }
    }
  }

  // epilogue: lane-reduce l_part over the 16 kpos lanes, then scale + store
  float inv[4];
#pragma unroll
  for (int r = 0; r < 4; r++) {
    float ps = l_part[r];
    ps += __shfl_xor(ps, 1);
    ps += __shfl_xor(ps, 2);
    ps += __shfl_xor(ps, 4);
    ps += __shfl_xor(ps, 8);
    inv[r] = 1.0f / ps;
  }
#pragma unroll
  for (int db = 0; db < 4; db++)
#pragma unroll
    for (int r = 0; r < 4; r++) {
      size_t idx = (size_t)(b * 2048 + q0 + w * 16 + q4 * 4 + r) * 1024 +
                   h * 64 + db * 16 + l15;
      ctx[idx] = f2bf(vacc[db][r] * inv[r]);
    }
}

// ---------------------------------------------------------------------------
// Launch
// ---------------------------------------------------------------------------
extern "C" void kernel_launch(void* const* d_in, const int* in_sizes, int n_in,
                              void* d_out, int out_size, void* d_ws, size_t ws_size,
                              hipStream_t stream) {
  (void)in_sizes; (void)n_in; (void)out_size; (void)ws_size;
  const float* inputs  = (const float*)d_in[0];
  const float* wq      = (const float*)d_in[1];
  const float* wk      = (const float*)d_in[2];
  const float* wv      = (const float*)d_in[3];
  const float* wo      = (const float*)d_in[4];
  const float* wi      = (const float*)d_in[5];
  const float* wmo     = (const float*)d_in[6];
  const float* rel_emb = (const float*)d_in[7];
  float* out = (float*)d_out;
  char* ws = (char*)d_ws;

  const size_t MB = 1ull << 20;
  short* x16    = (short*)(ws + 0);         // 16 MB  [8192][1024]
  short* qkv    = (short*)(ws + 16 * MB);   // 48 MB  [8192][3072]
  short* hidden = (short*)(ws + 16 * MB);   // 64 MB  [8192][4096] overlay (qkv+vT dead)
  short* vT     = (short*)(ws + 64 * MB);   // 16 MB  [64][64][2048]
  short* wqkvt  = (short*)(ws + 80 * MB);   // 6 MB   [3072][1024]
  short* wit    = (short*)(ws + 86 * MB);   // 8 MB   [4096][1024]
  short* wcat   = (short*)(ws + 94 * MB);   // 10.5MB [1024][5120] = [wo^T | wmo^T]
  float* btab   = (float*)(ws + 105 * MB);  // 128 KB [16][2048] (pre-scaled)
  short* ctx    = (short*)(ws + 106 * MB);  // 16 MB  [8192][1024]

  cvt_x_kernel<<<8192, 256, 0, stream>>>(inputs, x16);
  transpose_f2b_kernel<<<dim3(32, 32), 256, 0, stream>>>(wq, wqkvt, 1024, 1024, 1024);
  transpose_f2b_kernel<<<dim3(32, 32), 256, 0, stream>>>(wk, wqkvt + 1024 * 1024, 1024, 1024, 1024);
  transpose_f2b_kernel<<<dim3(32, 32), 256, 0, stream>>>(wv, wqkvt + 2 * 1024 * 1024, 1024, 1024, 1024);
  transpose_f2b_kernel<<<dim3(128, 32), 256, 0, stream>>>(wi, wit, 1024, 4096, 1024);
  transpose_f2b_kernel<<<dim3(32, 32), 256, 0, stream>>>(wo, wcat, 1024, 1024, 5120);
  transpose_f2b_kernel<<<dim3(32, 128), 256, 0, stream>>>(wmo, wcat + 1024, 4096, 1024, 5120);
  bias_kernel<<<128, 256, 0, stream>>>(rel_emb, btab);

  // qkv = x @ [wq|wk|wv]
  gemm_bt_kernel<0><<<dim3(24, 64), 256, 0, stream>>>(x16, wqkvt, 3072, 1024, qkv);
  transpose_v_kernel<<<dim3(64, 2, 64), 256, 0, stream>>>(qkv, vT);
  attn_kernel<<<dim3(64, 32), 256, 0, stream>>>(qkv, vT, btab, ctx);
  // hidden = relu(x @ wi)
  gemm_bt_kernel<1><<<dim3(32, 64), 256, 0, stream>>>(x16, wit, 4096, 1024, hidden);
  // out = [ctx|hidden] @ wcat^T + inputs
  gemm_cat_kernel<<<dim3(8, 64), 256, 0, stream>>>(ctx, hidden, wcat, inputs, out);
}

// Round 5
// 441.740 us; speedup vs baseline: 1.3191x; 1.1088x over previous
//
#include <hip/hip_runtime.h>
#include <stdint.h>

typedef short bf16x8 __attribute__((ext_vector_type(8)));
typedef float f32x4 __attribute__((ext_vector_type(4)));

// RNE float -> bf16 (raw bits in short)
__device__ __forceinline__ short f2bf(float f) {
  unsigned int u = __float_as_uint(f);
  u = (u + 0x7FFFu + ((u >> 16) & 1u)) >> 16;
  return (short)u;
}

// async global->LDS, 16B per lane. LDS dest = wave-uniform base + lane*16.
__device__ __forceinline__ void gload_lds16(const void* g, void* l) {
  __builtin_amdgcn_global_load_lds((const __attribute__((address_space(1))) void*)g,
                                   (__attribute__((address_space(3))) void*)l, 16, 0, 0);
}
// async global->LDS, 4B per lane.
__device__ __forceinline__ void gload_lds4(const void* g, void* l) {
  __builtin_amdgcn_global_load_lds((const __attribute__((address_space(1))) void*)g,
                                   (__attribute__((address_space(3))) void*)l, 4, 0, 0);
}

// ---------------------------------------------------------------------------
// Mega prep kernel: flat 1D grid of 20608 blocks x 256 threads.
//   [0, 8192)        cvt_x: fp32 -> bf16, 4 elems/thread
//   [8192, 20480)    weight transposes (bf16), segment table below
//   [20480, 20608)   T5 bias table (pre-scaled for exp2 softmax)
// ---------------------------------------------------------------------------
__global__ void prep_kernel(const float* __restrict__ inputs, const float* __restrict__ wq,
                            const float* __restrict__ wk, const float* __restrict__ wv,
                            const float* __restrict__ wi, const float* __restrict__ wo,
                            const float* __restrict__ wmo, const float* __restrict__ rel_emb,
                            short* __restrict__ x16, short* __restrict__ wcat1,
                            short* __restrict__ wcat, float* __restrict__ btab) {
  const int t = threadIdx.x;
  int id = blockIdx.x;

  if (id < 8192) {  // ---- cvt_x ----
    int i = id * 256 + t;
    float4 v = ((const float4*)inputs)[i];
    short4 o;
    o.x = f2bf(v.x); o.y = f2bf(v.y); o.z = f2bf(v.z); o.w = f2bf(v.w);
    ((short4*)x16)[i] = o;
    return;
  }
  id -= 8192;

  if (id >= 12288) {  // ---- bias table ----
    int i = (id - 12288) * 256 + t;  // 16*2048
    int h = i >> 11, n = i & 2047;
    int bucket;
    if (n < 16) {
      bucket = n;
    } else {
      float tv = logf((float)n * 0.0625f) * (16.0f / 2.0794415416798357f);
      bucket = 16 + (int)tv;
      if (bucket > 31) bucket = 31;
    }
    btab[i] = rel_emb[bucket * 16 + h] * 1.4426950408889634f - 28.853900817779268f;
    return;
  }

  // ---- weight transpose: out[c*ldout + r] = bf16(in[r][c]) ----
  const float* in; short* out; int C, ldout, bx, by;
  if (id < 1024)      { in = wq;  out = wcat1;                C = 1024; ldout = 1024; int r = id;         bx = r & 31;  by = r >> 5; }
  else if (id < 2048) { in = wk;  out = wcat1 + 1024 * 1024;  C = 1024; ldout = 1024; int r = id - 1024;  bx = r & 31;  by = r >> 5; }
  else if (id < 3072) { in = wv;  out = wcat1 + 2048 * 1024;  C = 1024; ldout = 1024; int r = id - 2048;  bx = r & 31;  by = r >> 5; }
  else if (id < 7168) { in = wi;  out = wcat1 + 3072 * 1024;  C = 4096; ldout = 1024; int r = id - 3072;  bx = r & 127; by = r >> 7; }
  else if (id < 8192) { in = wo;  out = wcat;                 C = 1024; ldout = 5120; int r = id - 7168;  bx = r & 31;  by = r >> 5; }
  else                { in = wmo; out = wcat + 1024;          C = 1024; ldout = 5120; int r = id - 8192;  bx = r & 31;  by = r >> 5; }

  __shared__ float tile[32][33];
  int tx = t & 31, ty = t >> 5;
  int c0 = bx * 32, r0 = by * 32;
#pragma unroll
  for (int j = 0; j < 4; j++)
    tile[ty + j * 8][tx] = in[(size_t)(r0 + ty + j * 8) * C + c0 + tx];
  __syncthreads();
#pragma unroll
  for (int j = 0; j < 4; j++)
    out[(size_t)(c0 + ty + j * 8) * ldout + r0 + tx] = f2bf(tile[tx][ty + j * 8]);
}

// vT[bh][d][l] = qkv[b*2048+l][2048 + h*64 + d]
__global__ void transpose_v_kernel(const short* __restrict__ qkv, short* __restrict__ vT) {
  __shared__ short tile[32][33];
  int tx = threadIdx.x & 31, ty = threadIdx.x >> 5;
  int l0 = blockIdx.x * 32, d0 = blockIdx.y * 32;
  int bh = blockIdx.z, b = bh >> 4, h = bh & 15;
#pragma unroll
  for (int j = 0; j < 4; j++)
    tile[ty + j * 8][tx] =
        qkv[(size_t)(b * 2048 + l0 + ty + j * 8) * 3072 + 2048 + h * 64 + d0 + tx];
  __syncthreads();
#pragma unroll
  for (int j = 0; j < 4; j++)
    vT[((size_t)bh * 64 + d0 + ty + j * 8) * 2048 + l0 + tx] = tile[tx][ty + j * 8];
}

// ---------------------------------------------------------------------------
// Fused QKV+MLP GEMM: A = x16 [8192][1024], Bt = wcat1 [7168][1024].
// nBase = (blockIdx.x + xoff)*128. Columns [0,3072) -> qkv (bf16, ld 3072);
// columns [3072,7168) -> hidden (relu bf16, ld 4096).
// 128x128 tile, BK=64, global_load_lds staging, XOR-rotate swizzle.
// ---------------------------------------------------------------------------
__global__ __launch_bounds__(256, 3)
void gemm_qkvmlp_kernel(const short* __restrict__ A, const short* __restrict__ Bt,
                        short* __restrict__ qkv, short* __restrict__ hidden, int xoff) {
  __shared__ short lA[128 * 64];
  __shared__ short lB[128 * 64];
  const int t = threadIdx.x;
  const int w = t >> 6, lane = t & 63;
  const int q4 = lane >> 4, l15 = lane & 15;
  const int mBase = blockIdx.y * 128, nBase = (blockIdx.x + xoff) * 128;
  const int wm = (w >> 1) * 64, wn = (w & 1) * 64;
  const int K = 1024;

  const f32x4 fzero = {0.f, 0.f, 0.f, 0.f};
  f32x4 acc[4][4];
#pragma unroll
  for (int i = 0; i < 4; i++)
#pragma unroll
    for (int j = 0; j < 4; j++) acc[i][j] = fzero;

  for (int k0 = 0; k0 < K; k0 += 64) {
    __syncthreads();
#pragma unroll
    for (int p = 0; p < 4; p++) {
      int c = p * 256 + t;
      int row = c >> 3;
      int kc = ((c & 7) - row) & 7;  // logical k-chunk stored at slot c&7
      gload_lds16(A + (size_t)(mBase + row) * K + k0 + kc * 8, lA + (size_t)(c - lane) * 8);
      gload_lds16(Bt + (size_t)(nBase + row) * K + k0 + kc * 8, lB + (size_t)(c - lane) * 8);
    }
    __syncthreads();
#pragma unroll
    for (int ks = 0; ks < 2; ks++) {
      bf16x8 af[4], bfr[4];
#pragma unroll
      for (int mi = 0; mi < 4; mi++) {
        int row = wm + mi * 16 + l15;
        af[mi] = *(const bf16x8*)&lA[row * 64 + ((ks * 4 + q4 + row) & 7) * 8];
      }
#pragma unroll
      for (int ni = 0; ni < 4; ni++) {
        int row = wn + ni * 16 + l15;
        bfr[ni] = *(const bf16x8*)&lB[row * 64 + ((ks * 4 + q4 + row) & 7) * 8];
      }
#pragma unroll
      for (int mi = 0; mi < 4; mi++)
#pragma unroll
        for (int ni = 0; ni < 4; ni++)
          acc[mi][ni] =
              __builtin_amdgcn_mfma_f32_16x16x32_bf16(af[mi], bfr[ni], acc[mi][ni], 0, 0, 0);
    }
  }

  const bool isMlp = nBase >= 3072;
  short* Cb = isMlp ? hidden : qkv;
  const int ldC = isMlp ? 4096 : 3072;
  const int ncol = isMlp ? nBase - 3072 : nBase;
#pragma unroll
  for (int mi = 0; mi < 4; mi++)
#pragma unroll
    for (int ni = 0; ni < 4; ni++) {
#pragma unroll
      for (int r = 0; r < 4; r++) {
        size_t idx = (size_t)(mBase + wm + mi * 16 + q4 * 4 + r) * ldC +
                     (ncol + wn + ni * 16 + l15);
        float v = acc[mi][ni][r];
        if (isMlp && v < 0.f) v = 0.f;
        Cb[idx] = f2bf(v);
      }
    }
}

// ---------------------------------------------------------------------------
// Fused final GEMM: out[M][1024] = [ctx | hidden] @ wcat^T + inputs
// ---------------------------------------------------------------------------
__global__ __launch_bounds__(256, 3)
void gemm_cat_kernel(const short* __restrict__ ctx, const short* __restrict__ hidden,
                     const short* __restrict__ wcat, const float* __restrict__ resid,
                     float* __restrict__ out) {
  __shared__ short lA[128 * 64];
  __shared__ short lB[128 * 64];
  const int t = threadIdx.x;
  const int w = t >> 6, lane = t & 63;
  const int q4 = lane >> 4, l15 = lane & 15;
  const int mBase = blockIdx.y * 128, nBase = blockIdx.x * 128;
  const int wm = (w >> 1) * 64, wn = (w & 1) * 64;

  const f32x4 fzero = {0.f, 0.f, 0.f, 0.f};
  f32x4 acc[4][4];
#pragma unroll
  for (int i = 0; i < 4; i++)
#pragma unroll
    for (int j = 0; j < 4; j++) acc[i][j] = fzero;

  for (int k0 = 0; k0 < 5120; k0 += 64) {
    const short* Abase = (k0 < 1024) ? (ctx + k0) : (hidden + (k0 - 1024));
    const size_t lda = (k0 < 1024) ? 1024 : 4096;
    __syncthreads();
#pragma unroll
    for (int p = 0; p < 4; p++) {
      int c = p * 256 + t;
      int row = c >> 3;
      int kc = ((c & 7) - row) & 7;
      gload_lds16(Abase + (size_t)(mBase + row) * lda + kc * 8, lA + (size_t)(c - lane) * 8);
      gload_lds16(wcat + (size_t)(nBase + row) * 5120 + k0 + kc * 8,
                  lB + (size_t)(c - lane) * 8);
    }
    __syncthreads();
#pragma unroll
    for (int ks = 0; ks < 2; ks++) {
      bf16x8 af[4], bfr[4];
#pragma unroll
      for (int mi = 0; mi < 4; mi++) {
        int row = wm + mi * 16 + l15;
        af[mi] = *(const bf16x8*)&lA[row * 64 + ((ks * 4 + q4 + row) & 7) * 8];
      }
#pragma unroll
      for (int ni = 0; ni < 4; ni++) {
        int row = wn + ni * 16 + l15;
        bfr[ni] = *(const bf16x8*)&lB[row * 64 + ((ks * 4 + q4 + row) & 7) * 8];
      }
#pragma unroll
      for (int mi = 0; mi < 4; mi++)
#pragma unroll
        for (int ni = 0; ni < 4; ni++)
          acc[mi][ni] =
              __builtin_amdgcn_mfma_f32_16x16x32_bf16(af[mi], bfr[ni], acc[mi][ni], 0, 0, 0);
    }
  }

#pragma unroll
  for (int mi = 0; mi < 4; mi++)
#pragma unroll
    for (int ni = 0; ni < 4; ni++) {
#pragma unroll
      for (int r = 0; r < 4; r++) {
        size_t idx = (size_t)(mBase + wm + mi * 16 + q4 * 4 + r) * 1024 +
                     (nBase + wn + ni * 16 + l15);
        out[idx] = acc[mi][ni][r] + resid[idx];
      }
    }
}

// ---------------------------------------------------------------------------
// Flash attention, causal + T5 relpos bias.  K-tile 128, Q-tile 64, 4 waves.
// global_load_lds staging, XOR-rotate swizzle, fixed-shift exp2 softmax.
// ---------------------------------------------------------------------------
__global__ __launch_bounds__(256, 3)
void attn_kernel(const short* __restrict__ qkv, const short* __restrict__ vT,
                 const float* __restrict__ bias_tab, short* __restrict__ ctx) {
  __shared__ short lK[128 * 64];     // [kpos][d], swizzle-8
  __shared__ short lV[64 * 128];     // [d][kpos], swizzle-16
  __shared__ short lP[4][16 * 128];  // per-wave P round-trip, swizzle-16
  __shared__ float lBias[192];

  const int t = threadIdx.x, w = t >> 6, lane = t & 63;
  const int q4 = lane >> 4, l15 = lane & 15;
  const int bh = blockIdx.x;            // 0..63
  const int qt = 31 - blockIdx.y;       // heavy blocks first
  const int b = bh >> 4, h = bh & 15;
  const int q0 = qt * 64;
  const int ntiles = (qt + 2) >> 1;     // 128-wide K tiles covering [0, q0+64)
  const f32x4 fzero = {0.f, 0.f, 0.f, 0.f};
  const float C1 = 0.125f * 1.4426950408889634f;  // score scale * log2(e)

  const size_t qrow = (size_t)(b * 2048 + q0 + w * 16 + l15) * 3072 + h * 64;
  bf16x8 aq0 = *(const bf16x8*)(qkv + qrow + q4 * 8);
  bf16x8 aq1 = *(const bf16x8*)(qkv + qrow + 32 + q4 * 8);

  f32x4 vacc[4];
#pragma unroll
  for (int db = 0; db < 4; db++) vacc[db] = fzero;
  float l_part[4] = {0.f, 0.f, 0.f, 0.f};

  const float* btab = bias_tab + h * 2048;
  const int qrow0 = q0 + w * 16 + q4 * 4;
  const int bofs = w * 16 + q4 * 4 + 127 - l15;

  for (int kt = 0; kt < ntiles; kt++) {
    __syncthreads();  // prior tile's LDS reads done
#pragma unroll
    for (int p = 0; p < 4; p++) {
      int c = p * 256 + t;
      int row = c >> 3;
      int kc = ((c & 7) - row) & 7;
      gload_lds16(qkv + (size_t)(b * 2048 + kt * 128 + row) * 3072 + 1024 + h * 64 + kc * 8,
                  lK + (size_t)(c - lane) * 8);
    }
#pragma unroll
    for (int p = 0; p < 4; p++) {
      int c = p * 256 + t;
      int d = c >> 4;
      int vc = ((c & 15) - d) & 15;
      gload_lds16(vT + ((size_t)bh * 64 + d) * 2048 + kt * 128 + vc * 8,
                  lV + (size_t)(c - lane) * 8);
    }
    if (w < 3) {
      int d = q0 - kt * 128 - 127 + t;
      d = d < 0 ? 0 : (d > 2047 ? 2047 : d);
      gload_lds4(btab + d, lBias + (t - lane));
    }
    __syncthreads();  // staging visible (barrier drains vmcnt)

    // S = Q K^T ; p = exp2(S*C1 + biaspre) ; causal mask -> 0
    float pr[8][4];
#pragma unroll
    for (int nb = 0; nb < 8; nb++) {
      int row = nb * 16 + l15;
      bf16x8 bk0 = *(const bf16x8*)&lK[row * 64 + ((q4 + row) & 7) * 8];
      bf16x8 bk1 = *(const bf16x8*)&lK[row * 64 + ((q4 + 4 + row) & 7) * 8];
      f32x4 f = fzero;
      f = __builtin_amdgcn_mfma_f32_16x16x32_bf16(aq0, bk0, f, 0, 0, 0);
      f = __builtin_amdgcn_mfma_f32_16x16x32_bf16(aq1, bk1, f, 0, 0, 0);
      const int kcol = kt * 128 + row;
#pragma unroll
      for (int r = 0; r < 4; r++) {
        int dist = (qrow0 + r) - kcol;
        float tv = f[r] * C1 + lBias[bofs + r - nb * 16];
        float pv = __builtin_amdgcn_exp2f(tv);
        pv = (dist < 0) ? 0.f : pv;
        pr[nb][r] = pv;
        l_part[r] += pv;
      }
    }

    // P: C-layout -> LDS -> A-layout (per-wave, swizzle-16)
    short* lPw = lP[w];
#pragma unroll
    for (int nb = 0; nb < 8; nb++) {
      int c = nb * 2 + (l15 >> 3);
#pragma unroll
      for (int r = 0; r < 4; r++) {
        int row = q4 * 4 + r;
        lPw[row * 128 + ((c + row) & 15) * 8 + (l15 & 7)] = f2bf(pr[nb][r]);
      }
    }

    bf16x8 ap[4];
#pragma unroll
    for (int ks2 = 0; ks2 < 4; ks2++)
      ap[ks2] = *(const bf16x8*)&lPw[l15 * 128 + ((ks2 * 4 + q4 + l15) & 15) * 8];
#pragma unroll
    for (int db = 0; db < 4; db++) {
      int row = db * 16 + l15;
#pragma unroll
      for (int ks2 = 0; ks2 < 4; ks2++) {
        bf16x8 bv = *(const bf16x8*)&lV[row * 128 + ((ks2 * 4 + q4 + row) & 15) * 8];
        vacc[db] = __builtin_amdgcn_mfma_f32_16x16x32_bf16(ap[ks2], bv, vacc[db], 0, 0, 0);
      }
    }
  }

  float inv[4];
#pragma unroll
  for (int r = 0; r < 4; r++) {
    float ps = l_part[r];
    ps += __shfl_xor(ps, 1);
    ps += __shfl_xor(ps, 2);
    ps += __shfl_xor(ps, 4);
    ps += __shfl_xor(ps, 8);
    inv[r] = 1.0f / ps;
  }
#pragma unroll
  for (int db = 0; db < 4; db++)
#pragma unroll
    for (int r = 0; r < 4; r++) {
      size_t idx = (size_t)(b * 2048 + q0 + w * 16 + q4 * 4 + r) * 1024 +
                   h * 64 + db * 16 + l15;
      ctx[idx] = f2bf(vacc[db][r] * inv[r]);
    }
}

// ---------------------------------------------------------------------------
// Launch
// ---------------------------------------------------------------------------
extern "C" void kernel_launch(void* const* d_in, const int* in_sizes, int n_in,
                              void* d_out, int out_size, void* d_ws, size_t ws_size,
                              hipStream_t stream) {
  (void)in_sizes; (void)n_in; (void)out_size;
  const float* inputs  = (const float*)d_in[0];
  const float* wq      = (const float*)d_in[1];
  const float* wk      = (const float*)d_in[2];
  const float* wv      = (const float*)d_in[3];
  const float* wo      = (const float*)d_in[4];
  const float* wi      = (const float*)d_in[5];
  const float* wmo     = (const float*)d_in[6];
  const float* rel_emb = (const float*)d_in[7];
  float* out = (float*)d_out;
  char* ws = (char*)d_ws;
  const size_t MB = 1ull << 20;
  const bool big = ws_size >= 171 * MB;

  short *x16, *qkv, *hidden, *vT, *wcat1, *wcat, *ctx;
  float* btab;
  if (big) {
    // fused path: qkv + hidden live simultaneously; ctx overlays x16 (dead
    // after the fused GEMM, which completes before attn writes ctx)
    x16    = (short*)(ws + 0);         // 16 MB [8192][1024]
    ctx    = (short*)(ws + 0);         // 16 MB overlay
    qkv    = (short*)(ws + 16 * MB);   // 48 MB [8192][3072]
    vT     = (short*)(ws + 64 * MB);   // 16 MB [64][64][2048]
    hidden = (short*)(ws + 80 * MB);   // 64 MB [8192][4096]
    wcat1  = (short*)(ws + 144 * MB);  // 14 MB [7168][1024]
    wcat   = (short*)(ws + 158 * MB);  // 10.5 MB [1024][5120]
    btab   = (float*)(ws + 169 * MB);  // 128 KB
  } else {
    // round-4 layout: hidden overlays qkv (MLP GEMM runs after attn)
    x16    = (short*)(ws + 0);
    qkv    = (short*)(ws + 16 * MB);
    hidden = (short*)(ws + 16 * MB);   // overlay
    vT     = (short*)(ws + 64 * MB);
    wcat1  = (short*)(ws + 80 * MB);   // 14 MB
    wcat   = (short*)(ws + 94 * MB);
    btab   = (float*)(ws + 105 * MB);
    ctx    = (short*)(ws + 106 * MB);
  }

  prep_kernel<<<20608, 256, 0, stream>>>(inputs, wq, wk, wv, wi, wo, wmo, rel_emb,
                                         x16, wcat1, wcat, btab);
  if (big) {
    // one fused GEMM writes qkv and hidden
    gemm_qkvmlp_kernel<<<dim3(56, 64), 256, 0, stream>>>(x16, wcat1, qkv, hidden, 0);
    transpose_v_kernel<<<dim3(64, 2, 64), 256, 0, stream>>>(qkv, vT);
    attn_kernel<<<dim3(64, 32), 256, 0, stream>>>(qkv, vT, btab, ctx);
  } else {
    gemm_qkvmlp_kernel<<<dim3(24, 64), 256, 0, stream>>>(x16, wcat1, qkv, hidden, 0);
    transpose_v_kernel<<<dim3(64, 2, 64), 256, 0, stream>>>(qkv, vT);
    attn_kernel<<<dim3(64, 32), 256, 0, stream>>>(qkv, vT, btab, ctx);
    // MLP half after attn (hidden clobbers qkv region)
    gemm_qkvmlp_kernel<<<dim3(32, 64), 256, 0, stream>>>(x16, wcat1, qkv, hidden, 24);
  }
  gemm_cat_kernel<<<dim3(8, 64), 256, 0, stream>>>(ctx, hidden, wcat, inputs, out);
}

// Round 6
// 429.951 us; speedup vs baseline: 1.3552x; 1.0274x over previous
//
#include <hip/hip_runtime.h>
#include <stdint.h>

typedef short bf16x8 __attribute__((ext_vector_type(8)));
typedef float f32x4 __attribute__((ext_vector_type(4)));

// RNE float -> bf16 (raw bits in short)
__device__ __forceinline__ short f2bf(float f) {
  unsigned int u = __float_as_uint(f);
  u = (u + 0x7FFFu + ((u >> 16) & 1u)) >> 16;
  return (short)u;
}

// async global->LDS, 16B per lane. LDS dest = wave-uniform base + lane*16.
__device__ __forceinline__ void gload_lds16(const void* g, void* l) {
  __builtin_amdgcn_global_load_lds((const __attribute__((address_space(1))) void*)g,
                                   (__attribute__((address_space(3))) void*)l, 16, 0, 0);
}
// async global->LDS, 4B per lane.
__device__ __forceinline__ void gload_lds4(const void* g, void* l) {
  __builtin_amdgcn_global_load_lds((const __attribute__((address_space(1))) void*)g,
                                   (__attribute__((address_space(3))) void*)l, 4, 0, 0);
}

// XCD-aware work remap: blocks sharing an A-panel (same mIdx) get ids with the
// same id%8 -> same XCD (round-robin dispatch heuristic; perf-only).
// Requires gridDim.y == 64. mIdx in [0,64), nIdx in [0,gridDim.x).
__device__ __forceinline__ void xcd_remap(int& mIdx, int& nIdx) {
  int id = blockIdx.y * gridDim.x + blockIdx.x;
  int xcd = id & 7, local = id >> 3;
  mIdx = ((local & 7) << 3) | xcd;
  nIdx = local >> 3;
}

// ---------------------------------------------------------------------------
// Mega prep kernel: flat 1D grid of 20608 blocks x 256 threads.
// ---------------------------------------------------------------------------
__global__ void prep_kernel(const float* __restrict__ inputs, const float* __restrict__ wq,
                            const float* __restrict__ wk, const float* __restrict__ wv,
                            const float* __restrict__ wi, const float* __restrict__ wo,
                            const float* __restrict__ wmo, const float* __restrict__ rel_emb,
                            short* __restrict__ x16, short* __restrict__ wcat1,
                            short* __restrict__ wcat, float* __restrict__ btab) {
  const int t = threadIdx.x;
  int id = blockIdx.x;

  if (id < 8192) {  // ---- cvt_x ----
    int i = id * 256 + t;
    float4 v = ((const float4*)inputs)[i];
    short4 o;
    o.x = f2bf(v.x); o.y = f2bf(v.y); o.z = f2bf(v.z); o.w = f2bf(v.w);
    ((short4*)x16)[i] = o;
    return;
  }
  id -= 8192;

  if (id >= 12288) {  // ---- bias table (pre-scaled for exp2 softmax) ----
    int i = (id - 12288) * 256 + t;  // 16*2048
    int h = i >> 11, n = i & 2047;
    int bucket;
    if (n < 16) {
      bucket = n;
    } else {
      float tv = logf((float)n * 0.0625f) * (16.0f / 2.0794415416798357f);
      bucket = 16 + (int)tv;
      if (bucket > 31) bucket = 31;
    }
    btab[i] = rel_emb[bucket * 16 + h] * 1.4426950408889634f - 28.853900817779268f;
    return;
  }

  // ---- weight transpose: out[c*ldout + r] = bf16(in[r][c]) ----
  const float* in; short* out; int C, ldout, bx, by;
  if (id < 1024)      { in = wq;  out = wcat1;                C = 1024; ldout = 1024; int r = id;         bx = r & 31;  by = r >> 5; }
  else if (id < 2048) { in = wk;  out = wcat1 + 1024 * 1024;  C = 1024; ldout = 1024; int r = id - 1024;  bx = r & 31;  by = r >> 5; }
  else if (id < 3072) { in = wv;  out = wcat1 + 2048 * 1024;  C = 1024; ldout = 1024; int r = id - 2048;  bx = r & 31;  by = r >> 5; }
  else if (id < 7168) { in = wi;  out = wcat1 + 3072 * 1024;  C = 4096; ldout = 1024; int r = id - 3072;  bx = r & 127; by = r >> 7; }
  else if (id < 8192) { in = wo;  out = wcat;                 C = 1024; ldout = 5120; int r = id - 7168;  bx = r & 31;  by = r >> 5; }
  else                { in = wmo; out = wcat + 1024;          C = 1024; ldout = 5120; int r = id - 8192;  bx = r & 31;  by = r >> 5; }

  __shared__ float tile[32][33];
  int tx = t & 31, ty = t >> 5;
  int c0 = bx * 32, r0 = by * 32;
#pragma unroll
  for (int j = 0; j < 4; j++)
    tile[ty + j * 8][tx] = in[(size_t)(r0 + ty + j * 8) * C + c0 + tx];
  __syncthreads();
#pragma unroll
  for (int j = 0; j < 4; j++)
    out[(size_t)(c0 + ty + j * 8) * ldout + r0 + tx] = f2bf(tile[tx][ty + j * 8]);
}

// vT[bh][d][l] = qkv[b*2048+l][2048 + h*64 + d]
__global__ void transpose_v_kernel(const short* __restrict__ qkv, short* __restrict__ vT) {
  __shared__ short tile[32][33];
  int tx = threadIdx.x & 31, ty = threadIdx.x >> 5;
  int l0 = blockIdx.x * 32, d0 = blockIdx.y * 32;
  int bh = blockIdx.z, b = bh >> 4, h = bh & 15;
#pragma unroll
  for (int j = 0; j < 4; j++)
    tile[ty + j * 8][tx] =
        qkv[(size_t)(b * 2048 + l0 + ty + j * 8) * 3072 + 2048 + h * 64 + d0 + tx];
  __syncthreads();
#pragma unroll
  for (int j = 0; j < 4; j++)
    vT[((size_t)bh * 64 + d0 + ty + j * 8) * 2048 + l0 + tx] = tile[tx][ty + j * 8];
}

// ---------------------------------------------------------------------------
// Fused QKV+MLP GEMM: A = x16 [8192][1024], Bt = wcat1 [7168][1024].
// Columns [0,3072) -> qkv (bf16, ld 3072); [3072,7168) -> hidden (relu bf16).
// ---------------------------------------------------------------------------
__global__ __launch_bounds__(256, 3)
void gemm_qkvmlp_kernel(const short* __restrict__ A, const short* __restrict__ Bt,
                        short* __restrict__ qkv, short* __restrict__ hidden, int xoff) {
  __shared__ short lA[128 * 64];
  __shared__ short lB[128 * 64];
  const int t = threadIdx.x;
  const int w = t >> 6, lane = t & 63;
  const int q4 = lane >> 4, l15 = lane & 15;
  int mIdx, nIdx;
  xcd_remap(mIdx, nIdx);
  const int mBase = mIdx * 128, nBase = (nIdx + xoff) * 128;
  const int wm = (w >> 1) * 64, wn = (w & 1) * 64;
  const int K = 1024;

  const f32x4 fzero = {0.f, 0.f, 0.f, 0.f};
  f32x4 acc[4][4];
#pragma unroll
  for (int i = 0; i < 4; i++)
#pragma unroll
    for (int j = 0; j < 4; j++) acc[i][j] = fzero;

  for (int k0 = 0; k0 < K; k0 += 64) {
    __syncthreads();
#pragma unroll
    for (int p = 0; p < 4; p++) {
      int c = p * 256 + t;
      int row = c >> 3;
      int kc = ((c & 7) - row) & 7;  // logical k-chunk stored at slot c&7
      gload_lds16(A + (size_t)(mBase + row) * K + k0 + kc * 8, lA + (size_t)(c - lane) * 8);
      gload_lds16(Bt + (size_t)(nBase + row) * K + k0 + kc * 8, lB + (size_t)(c - lane) * 8);
    }
    __syncthreads();
#pragma unroll
    for (int ks = 0; ks < 2; ks++) {
      bf16x8 af[4], bfr[4];
#pragma unroll
      for (int mi = 0; mi < 4; mi++) {
        int row = wm + mi * 16 + l15;
        af[mi] = *(const bf16x8*)&lA[row * 64 + ((ks * 4 + q4 + row) & 7) * 8];
      }
#pragma unroll
      for (int ni = 0; ni < 4; ni++) {
        int row = wn + ni * 16 + l15;
        bfr[ni] = *(const bf16x8*)&lB[row * 64 + ((ks * 4 + q4 + row) & 7) * 8];
      }
#pragma unroll
      for (int mi = 0; mi < 4; mi++)
#pragma unroll
        for (int ni = 0; ni < 4; ni++)
          acc[mi][ni] =
              __builtin_amdgcn_mfma_f32_16x16x32_bf16(af[mi], bfr[ni], acc[mi][ni], 0, 0, 0);
    }
  }

  const bool isMlp = nBase >= 3072;
  short* Cb = isMlp ? hidden : qkv;
  const int ldC = isMlp ? 4096 : 3072;
  const int ncol = isMlp ? nBase - 3072 : nBase;
#pragma unroll
  for (int mi = 0; mi < 4; mi++)
#pragma unroll
    for (int ni = 0; ni < 4; ni++) {
#pragma unroll
      for (int r = 0; r < 4; r++) {
        size_t idx = (size_t)(mBase + wm + mi * 16 + q4 * 4 + r) * ldC +
                     (ncol + wn + ni * 16 + l15);
        float v = acc[mi][ni][r];
        if (isMlp && v < 0.f) v = 0.f;
        Cb[idx] = f2bf(v);
      }
    }
}

// ---------------------------------------------------------------------------
// Fused final GEMM: out[M][1024] = [ctx | hidden] @ wcat^T + inputs
// ---------------------------------------------------------------------------
__global__ __launch_bounds__(256, 3)
void gemm_cat_kernel(const short* __restrict__ ctx, const short* __restrict__ hidden,
                     const short* __restrict__ wcat, const float* __restrict__ resid,
                     float* __restrict__ out) {
  __shared__ short lA[128 * 64];
  __shared__ short lB[128 * 64];
  const int t = threadIdx.x;
  const int w = t >> 6, lane = t & 63;
  const int q4 = lane >> 4, l15 = lane & 15;
  int mIdx, nIdx;
  xcd_remap(mIdx, nIdx);
  const int mBase = mIdx * 128, nBase = nIdx * 128;
  const int wm = (w >> 1) * 64, wn = (w & 1) * 64;

  const f32x4 fzero = {0.f, 0.f, 0.f, 0.f};
  f32x4 acc[4][4];
#pragma unroll
  for (int i = 0; i < 4; i++)
#pragma unroll
    for (int j = 0; j < 4; j++) acc[i][j] = fzero;

  for (int k0 = 0; k0 < 5120; k0 += 64) {
    const short* Abase = (k0 < 1024) ? (ctx + k0) : (hidden + (k0 - 1024));
    const size_t lda = (k0 < 1024) ? 1024 : 4096;
    __syncthreads();
#pragma unroll
    for (int p = 0; p < 4; p++) {
      int c = p * 256 + t;
      int row = c >> 3;
      int kc = ((c & 7) - row) & 7;
      gload_lds16(Abase + (size_t)(mBase + row) * lda + kc * 8, lA + (size_t)(c - lane) * 8);
      gload_lds16(wcat + (size_t)(nBase + row) * 5120 + k0 + kc * 8,
                  lB + (size_t)(c - lane) * 8);
    }
    __syncthreads();
#pragma unroll
    for (int ks = 0; ks < 2; ks++) {
      bf16x8 af[4], bfr[4];
#pragma unroll
      for (int mi = 0; mi < 4; mi++) {
        int row = wm + mi * 16 + l15;
        af[mi] = *(const bf16x8*)&lA[row * 64 + ((ks * 4 + q4 + row) & 7) * 8];
      }
#pragma unroll
      for (int ni = 0; ni < 4; ni++) {
        int row = wn + ni * 16 + l15;
        bfr[ni] = *(const bf16x8*)&lB[row * 64 + ((ks * 4 + q4 + row) & 7) * 8];
      }
#pragma unroll
      for (int mi = 0; mi < 4; mi++)
#pragma unroll
        for (int ni = 0; ni < 4; ni++)
          acc[mi][ni] =
              __builtin_amdgcn_mfma_f32_16x16x32_bf16(af[mi], bfr[ni], acc[mi][ni], 0, 0, 0);
    }
  }

#pragma unroll
  for (int mi = 0; mi < 4; mi++)
#pragma unroll
    for (int ni = 0; ni < 4; ni++) {
#pragma unroll
      for (int r = 0; r < 4; r++) {
        size_t idx = (size_t)(mBase + wm + mi * 16 + q4 * 4 + r) * 1024 +
                     (nBase + wn + ni * 16 + l15);
        out[idx] = acc[mi][ni][r] + resid[idx];
      }
    }
}

// ---------------------------------------------------------------------------
// Flash attention, causal + T5 relpos bias.  K-tile 64, Q-tile 64, 4 waves.
// Small LDS (24.5 KB) -> 5+ blocks/CU for cross-block MFMA/VALU overlap.
// global_load_lds staging, XOR-rotate swizzle-8, fixed-shift exp2 softmax.
// ---------------------------------------------------------------------------
__global__ __launch_bounds__(256, 5)
void attn_kernel(const short* __restrict__ qkv, const short* __restrict__ vT,
                 const float* __restrict__ bias_tab, short* __restrict__ ctx) {
  __shared__ short lK[64 * 64];     // [kpos][d], swizzle-8
  __shared__ short lV[64 * 64];     // [d][kpos], swizzle-8
  __shared__ short lP[4][16 * 64];  // per-wave P round-trip, swizzle-8
  __shared__ float lBias[128];

  const int t = threadIdx.x, w = t >> 6, lane = t & 63;
  const int q4 = lane >> 4, l15 = lane & 15;
  const int bh = blockIdx.x;            // 0..63
  const int qt = 31 - blockIdx.y;       // heavy blocks first
  const int b = bh >> 4, h = bh & 15;
  const int q0 = qt * 64;
  const int ntiles = qt + 1;            // 64-wide K tiles covering [0, q0+64)
  const f32x4 fzero = {0.f, 0.f, 0.f, 0.f};
  const float C1 = 0.125f * 1.4426950408889634f;  // score scale * log2(e)

  const size_t qrow = (size_t)(b * 2048 + q0 + w * 16 + l15) * 3072 + h * 64;
  bf16x8 aq0 = *(const bf16x8*)(qkv + qrow + q4 * 8);
  bf16x8 aq1 = *(const bf16x8*)(qkv + qrow + 32 + q4 * 8);

  f32x4 vacc[4];
#pragma unroll
  for (int db = 0; db < 4; db++) vacc[db] = fzero;
  float l_part[4] = {0.f, 0.f, 0.f, 0.f};

  const float* btab = bias_tab + h * 2048;
  const int qrow0 = q0 + w * 16 + q4 * 4;
  const int bofs = w * 16 + q4 * 4 + 63 - l15;

  for (int kt = 0; kt < ntiles; kt++) {
    __syncthreads();  // prior tile's LDS reads done
    // K tile: 64 rows x 64 d, swizzle-8
#pragma unroll
    for (int p = 0; p < 2; p++) {
      int c = p * 256 + t;
      int row = c >> 3;
      int kc = ((c & 7) - row) & 7;
      gload_lds16(qkv + (size_t)(b * 2048 + kt * 64 + row) * 3072 + 1024 + h * 64 + kc * 8,
                  lK + (size_t)(c - lane) * 8);
    }
    // V^T tile: 64 d x 64 kpos, swizzle-8
#pragma unroll
    for (int p = 0; p < 2; p++) {
      int c = p * 256 + t;
      int d = c >> 3;
      int vc = ((c & 7) - d) & 7;
      gload_lds16(vT + ((size_t)bh * 64 + d) * 2048 + kt * 64 + vc * 8,
                  lV + (size_t)(c - lane) * 8);
    }
    // bias row (128 floats): lBias[i] = btab[clamp(q0 - kt*64 - 63 + i)]
    if (w < 2) {
      int d = q0 - kt * 64 - 63 + t;
      d = d < 0 ? 0 : (d > 2047 ? 2047 : d);
      gload_lds4(btab + d, lBias + (t - lane));
    }
    __syncthreads();  // staging visible (barrier drains vmcnt)

    // S = Q K^T ; p = exp2(S*C1 + biaspre) ; causal mask -> 0
    float pr[4][4];
#pragma unroll
    for (int nb = 0; nb < 4; nb++) {
      int row = nb * 16 + l15;
      bf16x8 bk0 = *(const bf16x8*)&lK[row * 64 + ((q4 + row) & 7) * 8];
      bf16x8 bk1 = *(const bf16x8*)&lK[row * 64 + ((q4 + 4 + row) & 7) * 8];
      f32x4 f = fzero;
      f = __builtin_amdgcn_mfma_f32_16x16x32_bf16(aq0, bk0, f, 0, 0, 0);
      f = __builtin_amdgcn_mfma_f32_16x16x32_bf16(aq1, bk1, f, 0, 0, 0);
      const int kcol = kt * 64 + row;
#pragma unroll
      for (int r = 0; r < 4; r++) {
        int dist = (qrow0 + r) - kcol;
        float tv = f[r] * C1 + lBias[bofs + r - nb * 16];
        float pv = __builtin_amdgcn_exp2f(tv);
        pv = (dist < 0) ? 0.f : pv;
        pr[nb][r] = pv;
        l_part[r] += pv;
      }
    }

    // P: C-layout -> LDS -> A-layout (per-wave, swizzle-8)
    short* lPw = lP[w];
#pragma unroll
    for (int nb = 0; nb < 4; nb++) {
      int c = nb * 2 + (l15 >> 3);
#pragma unroll
      for (int r = 0; r < 4; r++) {
        int row = q4 * 4 + r;
        lPw[row * 64 + ((c + row) & 7) * 8 + (l15 & 7)] = f2bf(pr[nb][r]);
      }
    }

    bf16x8 ap[2];
#pragma unroll
    for (int ks2 = 0; ks2 < 2; ks2++)
      ap[ks2] = *(const bf16x8*)&lPw[l15 * 64 + ((ks2 * 4 + q4 + l15) & 7) * 8];
#pragma unroll
    for (int db = 0; db < 4; db++) {
      int row = db * 16 + l15;
#pragma unroll
      for (int ks2 = 0; ks2 < 2; ks2++) {
        bf16x8 bv = *(const bf16x8*)&lV[row * 64 + ((ks2 * 4 + q4 + row) & 7) * 8];
        vacc[db] = __builtin_amdgcn_mfma_f32_16x16x32_bf16(ap[ks2], bv, vacc[db], 0, 0, 0);
      }
    }
  }

  float inv[4];
#pragma unroll
  for (int r = 0; r < 4; r++) {
    float ps = l_part[r];
    ps += __shfl_xor(ps, 1);
    ps += __shfl_xor(ps, 2);
    ps += __shfl_xor(ps, 4);
    ps += __shfl_xor(ps, 8);
    inv[r] = 1.0f / ps;
  }
#pragma unroll
  for (int db = 0; db < 4; db++)
#pragma unroll
    for (int r = 0; r < 4; r++) {
      size_t idx = (size_t)(b * 2048 + q0 + w * 16 + q4 * 4 + r) * 1024 +
                   h * 64 + db * 16 + l15;
      ctx[idx] = f2bf(vacc[db][r] * inv[r]);
    }
}

// ---------------------------------------------------------------------------
// Launch
// ---------------------------------------------------------------------------
extern "C" void kernel_launch(void* const* d_in, const int* in_sizes, int n_in,
                              void* d_out, int out_size, void* d_ws, size_t ws_size,
                              hipStream_t stream) {
  (void)in_sizes; (void)n_in; (void)out_size;
  const float* inputs  = (const float*)d_in[0];
  const float* wq      = (const float*)d_in[1];
  const float* wk      = (const float*)d_in[2];
  const float* wv      = (const float*)d_in[3];
  const float* wo      = (const float*)d_in[4];
  const float* wi      = (const float*)d_in[5];
  const float* wmo     = (const float*)d_in[6];
  const float* rel_emb = (const float*)d_in[7];
  float* out = (float*)d_out;
  char* ws = (char*)d_ws;
  const size_t MB = 1ull << 20;
  const bool big = ws_size >= 171 * MB;

  short *x16, *qkv, *hidden, *vT, *wcat1, *wcat, *ctx;
  float* btab;
  if (big) {
    // fused path: qkv + hidden live simultaneously; ctx overlays x16 (dead
    // after the fused GEMM, which completes before attn writes ctx)
    x16    = (short*)(ws + 0);         // 16 MB [8192][1024]
    ctx    = (short*)(ws + 0);         // 16 MB overlay
    qkv    = (short*)(ws + 16 * MB);   // 48 MB [8192][3072]
    vT     = (short*)(ws + 64 * MB);   // 16 MB [64][64][2048]
    hidden = (short*)(ws + 80 * MB);   // 64 MB [8192][4096]
    wcat1  = (short*)(ws + 144 * MB);  // 14 MB [7168][1024]
    wcat   = (short*)(ws + 158 * MB);  // 10.5 MB [1024][5120]
    btab   = (float*)(ws + 169 * MB);  // 128 KB
  } else {
    // fallback layout: hidden overlays qkv (MLP GEMM runs after attn)
    x16    = (short*)(ws + 0);
    qkv    = (short*)(ws + 16 * MB);
    hidden = (short*)(ws + 16 * MB);   // overlay
    vT     = (short*)(ws + 64 * MB);
    wcat1  = (short*)(ws + 80 * MB);   // 14 MB
    wcat   = (short*)(ws + 94 * MB);
    btab   = (float*)(ws + 105 * MB);
    ctx    = (short*)(ws + 106 * MB);
  }

  prep_kernel<<<20608, 256, 0, stream>>>(inputs, wq, wk, wv, wi, wo, wmo, rel_emb,
                                         x16, wcat1, wcat, btab);
  if (big) {
    gemm_qkvmlp_kernel<<<dim3(56, 64), 256, 0, stream>>>(x16, wcat1, qkv, hidden, 0);
    transpose_v_kernel<<<dim3(64, 2, 64), 256, 0, stream>>>(qkv, vT);
    attn_kernel<<<dim3(64, 32), 256, 0, stream>>>(qkv, vT, btab, ctx);
  } else {
    gemm_qkvmlp_kernel<<<dim3(24, 64), 256, 0, stream>>>(x16, wcat1, qkv, hidden, 0);
    transpose_v_kernel<<<dim3(64, 2, 64), 256, 0, stream>>>(qkv, vT);
    attn_kernel<<<dim3(64, 32), 256, 0, stream>>>(qkv, vT, btab, ctx);
    gemm_qkvmlp_kernel<<<dim3(32, 64), 256, 0, stream>>>(x16, wcat1, qkv, hidden, 24);
  }
  gemm_cat_kernel<<<dim3(8, 64), 256, 0, stream>>>(ctx, hidden, wcat, inputs, out);
}